// Round 1
// baseline (260.740 us; speedup 1.0000x reference)
//
#include <hip/hip_runtime.h>
#include <hip/hip_bf16.h>
#include <stdint.h>

#define B_SZ 8192
#define D_SZ 512
#define H_SZ 512
#define PRE_LD 2560   // 5 gate blocks of 512 columns

typedef __attribute__((ext_vector_type(8))) __bf16 bf16x8;
typedef __attribute__((ext_vector_type(4))) float f32x4;

__device__ __forceinline__ unsigned short f2bf(float f) {
  unsigned u = __builtin_bit_cast(unsigned, f);
  u += 0x7FFFu + ((u >> 16) & 1u);   // RNE (inputs finite)
  return (unsigned short)(u >> 16);
}
__device__ __forceinline__ float bf2f(unsigned short h) {
  unsigned u = ((unsigned)h) << 16;
  return __builtin_bit_cast(float, u);
}
__device__ __forceinline__ float sigf(float x) { return 1.0f / (1.0f + __expf(-x)); }

// async 16B global->LDS (wave-uniform LDS base + lane*16)
__device__ __forceinline__ void async_ld16(const unsigned short* g, unsigned short* l) {
  __builtin_amdgcn_global_load_lds(
      (const __attribute__((address_space(1))) unsigned int*)g,
      (__attribute__((address_space(3))) unsigned int*)l, 16, 0, 0);
}

// ---------------- cast/pack kernels ----------------
__global__ void pack_xh(const float* __restrict__ x, const float* __restrict__ h,
                        unsigned short* __restrict__ Xb, unsigned short* __restrict__ Hb) {
  int i = (blockIdx.x * 256 + threadIdx.x) * 4;
  const float* s; unsigned short* d; int off;
  if (i < B_SZ * D_SZ) { s = x; d = Xb; off = i; }
  else                 { s = h; d = Hb; off = i - B_SZ * D_SZ; }
  float4 v = *(const float4*)(s + off);
  ushort4 o; o.x = f2bf(v.x); o.y = f2bf(v.y); o.z = f2bf(v.z); o.w = f2bf(v.w);
  *(ushort4*)(d + off) = o;
}

struct WSrcs { const float* s[9]; };

__global__ void pack_w(WSrcs ws, unsigned short* __restrict__ Wxc,
                       unsigned short* __restrict__ Whc, unsigned short* __restrict__ Wcob) {
  int i = (blockIdx.x * 256 + threadIdx.x) * 4;
  int seg = i >> 18;            // 512*512 = 262144 elems per segment
  int off = i & 262143;
  const float* s = ws.s[seg] + off;
  unsigned short* d;
  if (seg < 5)      d = Wxc + (size_t)seg * 262144 + off;
  else if (seg < 8) d = Whc + (size_t)(seg - 5) * 262144 + off;
  else              d = Wcob + off;
  float4 v = *(const float4*)s;
  ushort4 o; o.x = f2bf(v.x); o.y = f2bf(v.y); o.z = f2bf(v.z); o.w = f2bf(v.w);
  *(ushort4*)d = o;
}

// ---------------- GEMM: C[m, col_off+n] (+)= A[m,:] . W[n,:]  (bf16 in/out) ----------------
// 128x128 tile, BK=64, 256 threads (4 waves in 2x2), mfma_f32_16x16x32_bf16
template <bool ACCUM>
__global__ __launch_bounds__(256, 2) void gemm_bt(
    const unsigned short* __restrict__ A, const unsigned short* __restrict__ W,
    unsigned short* __restrict__ C, int K, int ldc, int col_off) {
  __shared__ bf16x8 sA[128 * 8];   // 128 rows x 64 k (8 chunks of 8 bf16)
  __shared__ bf16x8 sW[128 * 8];
  const int tid  = threadIdx.x;
  const int wave = tid >> 6, lane = tid & 63;
  const int ln15 = lane & 15, kq = lane >> 4;
  const int wr = wave >> 1, wc = wave & 1;
  const long bm = (long)blockIdx.y * 128;
  const long bn = (long)blockIdx.x * 128;

  f32x4 acc[4][4];
#pragma unroll
  for (int i = 0; i < 4; ++i)
#pragma unroll
    for (int j = 0; j < 4; ++j) acc[i][j] = (f32x4){0.f, 0.f, 0.f, 0.f};

  const int nK = K >> 6;
  for (int kt = 0; kt < nK; ++kt) {
    const int k0 = kt << 6;
    __syncthreads();   // previous compute done before LDS overwrite
#pragma unroll
    for (int it = 0; it < 4; ++it) {
      int f   = it * 256 + tid;        // 16B chunk index in tile
      int row = f >> 3;                // 8 chunks per 64-elem row
      int col = (f & 7) << 3;
      int ldsc = it * 256 + wave * 64; // wave-uniform chunk base; lane lands at +lane
      async_ld16(A + (size_t)(bm + row) * K + k0 + col, (unsigned short*)sA + (size_t)ldsc * 8);
      async_ld16(W + (size_t)(bn + row) * K + k0 + col, (unsigned short*)sW + (size_t)ldsc * 8);
    }
    __syncthreads();   // drains vmcnt(0) -> tiles ready
#pragma unroll
    for (int ko = 0; ko < 2; ++ko) {
      bf16x8 af[4], wf[4];
#pragma unroll
      for (int t = 0; t < 4; ++t)
        af[t] = sA[(wr * 64 + t * 16 + ln15) * 8 + ko * 4 + kq];
#pragma unroll
      for (int t = 0; t < 4; ++t)
        wf[t] = sW[(wc * 64 + t * 16 + ln15) * 8 + ko * 4 + kq];
#pragma unroll
      for (int i = 0; i < 4; ++i)
#pragma unroll
        for (int j = 0; j < 4; ++j)
          acc[i][j] = __builtin_amdgcn_mfma_f32_16x16x32_bf16(af[i], wf[j], acc[i][j], 0, 0, 0);
    }
  }
  // epilogue: C/D layout col=lane&15, row=(lane>>4)*4+reg
#pragma unroll
  for (int i = 0; i < 4; ++i) {
    const long r0 = bm + wr * 64 + i * 16 + kq * 4;
#pragma unroll
    for (int j = 0; j < 4; ++j) {
      const long c = bn + wc * 64 + j * 16 + ln15;
#pragma unroll
      for (int r = 0; r < 4; ++r) {
        size_t idx = (size_t)(r0 + r) * ldc + col_off + c;
        float v = acc[i][j][r];
        if (ACCUM) v += bf2f(C[idx]);
        C[idx] = f2bf(v);
      }
    }
  }
}

// ---------------- gate kernel (elementwise over B x H) ----------------
__global__ void gate_kernel(unsigned short* __restrict__ Pre,
                            const float* __restrict__ delta_t, const float* __restrict__ cell_s,
                            const float* __restrict__ bii, const float* __restrict__ bhi,
                            const float* __restrict__ big, const float* __restrict__ bhg,
                            const float* __restrict__ bio, const float* __restrict__ bho,
                            const float* __restrict__ Wto, const float* __restrict__ bto,
                            const float* __restrict__ bco,
                            const float* __restrict__ bit1, const float* __restrict__ Wtt1,
                            const float* __restrict__ bit2, const float* __restrict__ Wtt2,
                            float* __restrict__ out_cm, unsigned short* __restrict__ cmt_b) {
  int idx = blockIdx.x * 256 + threadIdx.x;
  int b = idx >> 9, h = idx & 511;
  size_t p = (size_t)b * PRE_LD;
  float dt = delta_t[b];
  float a1 = bf2f(Pre[p + h])        + bit1[h];
  float a2 = bf2f(Pre[p + 512 + h])  + bit2[h];
  float ai = bf2f(Pre[p + 1024 + h]) + bii[h] + bhi[h];
  float ag = bf2f(Pre[p + 1536 + h]) + big[h] + bhg[h];
  float ao = bf2f(Pre[p + 2048 + h]) + bio[h] + bho[h] + dt * Wto[h] + bto[h] + bco[h];
  float t1 = sigf(a1 + sigf(dt * Wtt1[h]));
  float t2 = sigf(a2 + sigf(dt * Wtt2[h]));
  float im = sigf(ai);
  float g  = tanhf(ag);
  float cs = cell_s[idx];
  float it1 = im * t1;
  float cmt = (1.f - it1) * cs + it1 * g;
  float cm  = (1.f - im) * cs + im * t2 * g;
  out_cm[idx] = cm;
  cmt_b[idx]  = f2bf(cmt);
  Pre[p + 2048 + h] = f2bf(ao);   // ao with ALL biases folded (incl. bco)
}

// ---------------- GEMM3 with om/hm epilogue ----------------
__global__ __launch_bounds__(256, 2) void gemm_out(
    const unsigned short* __restrict__ A /*cmt_b BxH*/, const unsigned short* __restrict__ W /*Wco HxH*/,
    const unsigned short* __restrict__ Pre, float* __restrict__ out_hm) {
  __shared__ bf16x8 sA[128 * 8];
  __shared__ bf16x8 sW[128 * 8];
  const int tid  = threadIdx.x;
  const int wave = tid >> 6, lane = tid & 63;
  const int ln15 = lane & 15, kq = lane >> 4;
  const int wr = wave >> 1, wc = wave & 1;
  const long bm = (long)blockIdx.y * 128;
  const long bn = (long)blockIdx.x * 128;
  const int K = H_SZ;

  f32x4 acc[4][4];
#pragma unroll
  for (int i = 0; i < 4; ++i)
#pragma unroll
    for (int j = 0; j < 4; ++j) acc[i][j] = (f32x4){0.f, 0.f, 0.f, 0.f};

  for (int kt = 0; kt < (K >> 6); ++kt) {
    const int k0 = kt << 6;
    __syncthreads();
#pragma unroll
    for (int it = 0; it < 4; ++it) {
      int f   = it * 256 + tid;
      int row = f >> 3;
      int col = (f & 7) << 3;
      int ldsc = it * 256 + wave * 64;
      async_ld16(A + (size_t)(bm + row) * K + k0 + col, (unsigned short*)sA + (size_t)ldsc * 8);
      async_ld16(W + (size_t)(bn + row) * K + k0 + col, (unsigned short*)sW + (size_t)ldsc * 8);
    }
    __syncthreads();
#pragma unroll
    for (int ko = 0; ko < 2; ++ko) {
      bf16x8 af[4], wf[4];
#pragma unroll
      for (int t = 0; t < 4; ++t)
        af[t] = sA[(wr * 64 + t * 16 + ln15) * 8 + ko * 4 + kq];
#pragma unroll
      for (int t = 0; t < 4; ++t)
        wf[t] = sW[(wc * 64 + t * 16 + ln15) * 8 + ko * 4 + kq];
#pragma unroll
      for (int i = 0; i < 4; ++i)
#pragma unroll
        for (int j = 0; j < 4; ++j)
          acc[i][j] = __builtin_amdgcn_mfma_f32_16x16x32_bf16(af[i], wf[j], acc[i][j], 0, 0, 0);
    }
  }
#pragma unroll
  for (int i = 0; i < 4; ++i) {
    const long r0 = bm + wr * 64 + i * 16 + kq * 4;
#pragma unroll
    for (int j = 0; j < 4; ++j) {
      const long c = bn + wc * 64 + j * 16 + ln15;
#pragma unroll
      for (int r = 0; r < 4; ++r) {
        long row = r0 + r;
        size_t idx = (size_t)row * H_SZ + c;
        float ao  = bf2f(Pre[(size_t)row * PRE_LD + 2048 + c]);
        float om  = sigf(ao + acc[i][j][r]);
        float cmt = bf2f(A[idx]);
        out_hm[idx] = om * tanhf(cmt);
      }
    }
  }
}

extern "C" void kernel_launch(void* const* d_in, const int* in_sizes, int n_in,
                              void* d_out, int out_size, void* d_ws, size_t ws_size,
                              hipStream_t stream) {
  const float* x    = (const float*)d_in[0];
  const float* dt   = (const float*)d_in[1];
  const float* hid  = (const float*)d_in[2];
  const float* cell = (const float*)d_in[3];
  const float* Wii  = (const float*)d_in[4];
  const float* bii  = (const float*)d_in[5];
  const float* Whi  = (const float*)d_in[6];
  const float* bhi  = (const float*)d_in[7];
  const float* Wig  = (const float*)d_in[8];
  const float* big  = (const float*)d_in[9];
  const float* Whg  = (const float*)d_in[10];
  const float* bhg  = (const float*)d_in[11];
  const float* Wio  = (const float*)d_in[12];
  const float* bio  = (const float*)d_in[13];
  const float* Who  = (const float*)d_in[14];
  const float* bho  = (const float*)d_in[15];
  const float* Wto  = (const float*)d_in[16];
  const float* bto  = (const float*)d_in[17];
  const float* Wco  = (const float*)d_in[18];
  const float* bco  = (const float*)d_in[19];
  const float* Wit1 = (const float*)d_in[20];
  const float* bit1 = (const float*)d_in[21];
  const float* Wtt1 = (const float*)d_in[22];
  const float* Wit2 = (const float*)d_in[23];
  const float* bit2 = (const float*)d_in[24];
  const float* Wtt2 = (const float*)d_in[25];

  char* wp = (char*)d_ws;
  unsigned short* Xb   = (unsigned short*)wp; wp += (size_t)B_SZ * D_SZ * 2;
  unsigned short* Hb   = (unsigned short*)wp; wp += (size_t)B_SZ * H_SZ * 2;
  unsigned short* Wxc  = (unsigned short*)wp; wp += (size_t)5 * H_SZ * D_SZ * 2;
  unsigned short* Whc  = (unsigned short*)wp; wp += (size_t)3 * H_SZ * H_SZ * 2;
  unsigned short* Wcob = (unsigned short*)wp; wp += (size_t)H_SZ * H_SZ * 2;
  unsigned short* Pre  = (unsigned short*)wp; wp += (size_t)B_SZ * PRE_LD * 2;
  unsigned short* Cmtb = (unsigned short*)wp; wp += (size_t)B_SZ * H_SZ * 2;

  float* out = (float*)d_out;

  pack_xh<<<(B_SZ * (D_SZ + H_SZ)) / 4 / 256, 256, 0, stream>>>(x, hid, Xb, Hb);
  WSrcs wsrc;
  wsrc.s[0] = Wit1; wsrc.s[1] = Wit2; wsrc.s[2] = Wii; wsrc.s[3] = Wig; wsrc.s[4] = Wio;
  wsrc.s[5] = Whi;  wsrc.s[6] = Whg;  wsrc.s[7] = Who; wsrc.s[8] = Wco;
  pack_w<<<(9 * H_SZ * D_SZ) / 4 / 256, 256, 0, stream>>>(wsrc, Wxc, Whc, Wcob);

  // Pre[:, 0:2560] = Xb @ Wxc^T
  gemm_bt<false><<<dim3(PRE_LD / 128, B_SZ / 128), 256, 0, stream>>>(Xb, Wxc, Pre, D_SZ, PRE_LD, 0);
  // Pre[:, 1024:2560] += Hb @ Whc^T
  gemm_bt<true><<<dim3((3 * H_SZ) / 128, B_SZ / 128), 256, 0, stream>>>(Hb, Whc, Pre, H_SZ, PRE_LD, 1024);

  gate_kernel<<<(B_SZ * H_SZ) / 256, 256, 0, stream>>>(
      Pre, dt, cell, bii, bhi, big, bhg, bio, bho, Wto, bto, bco, bit1, Wtt1, bit2, Wtt2,
      out + (size_t)B_SZ * H_SZ, Cmtb);

  // hm = sig(ao + cmt@Wco^T) * tanh(cmt)
  gemm_out<<<dim3(H_SZ / 128, B_SZ / 128), 256, 0, stream>>>(Cmtb, Wcob, Pre, out);
}

// Round 2
// 251.599 us; speedup vs baseline: 1.0363x; 1.0363x over previous
//
#include <hip/hip_runtime.h>
#include <hip/hip_bf16.h>
#include <stdint.h>

#define B_SZ 8192
#define D_SZ 512
#define H_SZ 512
#define KC 1024       // concatenated K (x | hidden)
#define NPRE 2560     // 5 gate blocks of 512 columns
#define PRE_LD 2560

typedef __attribute__((ext_vector_type(8))) __bf16 bf16x8;
typedef __attribute__((ext_vector_type(4))) float f32x4;

__device__ __forceinline__ unsigned short f2bf(float f) {
  unsigned u = __builtin_bit_cast(unsigned, f);
  u += 0x7FFFu + ((u >> 16) & 1u);   // RNE (inputs finite)
  return (unsigned short)(u >> 16);
}
__device__ __forceinline__ float bf2f(unsigned short h) {
  unsigned u = ((unsigned)h) << 16;
  return __builtin_bit_cast(float, u);
}
__device__ __forceinline__ float sigf(float x) { return 1.0f / (1.0f + __expf(-x)); }

// async 16B global->LDS (wave-uniform LDS base + lane*16)
__device__ __forceinline__ void async_ld16(const unsigned short* g, unsigned short* l) {
  __builtin_amdgcn_global_load_lds(
      (const __attribute__((address_space(1))) unsigned int*)g,
      (__attribute__((address_space(3))) unsigned int*)l, 16, 0, 0);
}

// ---------------- pack kernels ----------------
// Ab[b, 0:512] = bf16(x[b,:]);  Ab[b, 512:1024] = bf16(hidden[b,:])
__global__ void pack_xh(const float* __restrict__ x, const float* __restrict__ h,
                        unsigned short* __restrict__ Ab) {
  int i = (blockIdx.x * 256 + threadIdx.x) * 4;
  int b = i >> 10, c = i & 1023;
  const float* s = (c < 512) ? (x + (size_t)b * 512 + c)
                             : (h + (size_t)b * 512 + (c - 512));
  float4 v = *(const float4*)s;
  ushort4 o; o.x = f2bf(v.x); o.y = f2bf(v.y); o.z = f2bf(v.z); o.w = f2bf(v.w);
  *(ushort4*)(Ab + i) = o;
}

struct WSrcs { const float* wx[5]; const float* wh[3]; const float* wco; };

// Wall (2560 x 1024): rows [Wit1|0],[Wit2|0],[Wii|Whi],[Wig|Whg],[Wio|Who]; plus Wcob (512x512)
__global__ void pack_w(WSrcs ws, unsigned short* __restrict__ Wall,
                       unsigned short* __restrict__ Wcob) {
  int i = (blockIdx.x * 256 + threadIdx.x) * 4;
  if (i < NPRE * KC) {
    int row = i >> 10, c = i & 1023;
    int gate = row >> 9, r = row & 511;
    ushort4 o;
    if (c < 512) {
      float4 v = *(const float4*)(ws.wx[gate] + (size_t)r * 512 + c);
      o.x = f2bf(v.x); o.y = f2bf(v.y); o.z = f2bf(v.z); o.w = f2bf(v.w);
    } else if (gate >= 2) {
      float4 v = *(const float4*)(ws.wh[gate - 2] + (size_t)r * 512 + (c - 512));
      o.x = f2bf(v.x); o.y = f2bf(v.y); o.z = f2bf(v.z); o.w = f2bf(v.w);
    } else {
      o.x = 0; o.y = 0; o.z = 0; o.w = 0;
    }
    *(ushort4*)(Wall + i) = o;
  } else {
    int j = i - NPRE * KC;
    float4 v = *(const float4*)(ws.wco + j);
    ushort4 o; o.x = f2bf(v.x); o.y = f2bf(v.y); o.z = f2bf(v.z); o.w = f2bf(v.w);
    *(ushort4*)(Wcob + j) = o;
  }
}

// ---------------- GEMM: C[m, n] = A[m,:] . W[n,:]  (bf16 in/out) ----------------
// 128x128 tile, BK=64, 256 threads (4 waves, 2x2), mfma_f32_16x16x32_bf16
__global__ __launch_bounds__(256, 2) void gemm_bt(
    const unsigned short* __restrict__ A, const unsigned short* __restrict__ W,
    unsigned short* __restrict__ C, int K, int ldc) {
  __shared__ bf16x8 sA[128 * 8];   // 128 rows x 64 k
  __shared__ bf16x8 sW[128 * 8];
  const int tid  = threadIdx.x;
  const int wave = tid >> 6, lane = tid & 63;
  const int ln15 = lane & 15, kq = lane >> 4;
  const int wr = wave >> 1, wc = wave & 1;
  const long bm = (long)blockIdx.y * 128;
  const long bn = (long)blockIdx.x * 128;

  f32x4 acc[4][4];
#pragma unroll
  for (int i = 0; i < 4; ++i)
#pragma unroll
    for (int j = 0; j < 4; ++j) acc[i][j] = (f32x4){0.f, 0.f, 0.f, 0.f};

  const int nK = K >> 6;
  for (int kt = 0; kt < nK; ++kt) {
    const int k0 = kt << 6;
    __syncthreads();
#pragma unroll
    for (int it = 0; it < 4; ++it) {
      int f   = it * 256 + tid;        // 16B chunk index in tile
      int row = f >> 3;
      int col = (f & 7) << 3;
      int ldsc = it * 256 + wave * 64; // wave-uniform chunk base
      async_ld16(A + (size_t)(bm + row) * K + k0 + col, (unsigned short*)sA + (size_t)ldsc * 8);
      async_ld16(W + (size_t)(bn + row) * K + k0 + col, (unsigned short*)sW + (size_t)ldsc * 8);
    }
    __syncthreads();
#pragma unroll
    for (int ko = 0; ko < 2; ++ko) {
      bf16x8 af[4], wf[4];
#pragma unroll
      for (int t = 0; t < 4; ++t)
        af[t] = sA[(wr * 64 + t * 16 + ln15) * 8 + ko * 4 + kq];
#pragma unroll
      for (int t = 0; t < 4; ++t)
        wf[t] = sW[(wc * 64 + t * 16 + ln15) * 8 + ko * 4 + kq];
#pragma unroll
      for (int i = 0; i < 4; ++i)
#pragma unroll
        for (int j = 0; j < 4; ++j)
          acc[i][j] = __builtin_amdgcn_mfma_f32_16x16x32_bf16(af[i], wf[j], acc[i][j], 0, 0, 0);
    }
  }
  // C/D layout: col=lane&15, row=(lane>>4)*4+reg
#pragma unroll
  for (int i = 0; i < 4; ++i) {
    const long r0 = bm + wr * 64 + i * 16 + kq * 4;
#pragma unroll
    for (int j = 0; j < 4; ++j) {
      const long c = bn + wc * 64 + j * 16 + ln15;
#pragma unroll
      for (int r = 0; r < 4; ++r)
        C[(size_t)(r0 + r) * ldc + c] = f2bf(acc[i][j][r]);
    }
  }
}

// ---------------- gate kernel (4 elems/thread, vectorized) ----------------
__global__ void gate_kernel(unsigned short* __restrict__ Pre,
                            const float* __restrict__ delta_t, const float* __restrict__ cell_s,
                            const float* __restrict__ bii, const float* __restrict__ bhi,
                            const float* __restrict__ big, const float* __restrict__ bhg,
                            const float* __restrict__ bio, const float* __restrict__ bho,
                            const float* __restrict__ Wto, const float* __restrict__ bto,
                            const float* __restrict__ bco,
                            const float* __restrict__ bit1, const float* __restrict__ Wtt1,
                            const float* __restrict__ bit2, const float* __restrict__ Wtt2,
                            float* __restrict__ out_cm, unsigned short* __restrict__ cmt_b) {
  int i4 = (blockIdx.x * 256 + threadIdx.x) * 4;
  int b = i4 >> 9, h = i4 & 511;
  size_t p = (size_t)b * PRE_LD;
  float dt = delta_t[b];
  ushort4 u1 = *(const ushort4*)(Pre + p + h);
  ushort4 u2 = *(const ushort4*)(Pre + p + 512 + h);
  ushort4 ui = *(const ushort4*)(Pre + p + 1024 + h);
  ushort4 ug = *(const ushort4*)(Pre + p + 1536 + h);
  ushort4 uo = *(const ushort4*)(Pre + p + 2048 + h);
  float4 cs  = *(const float4*)(cell_s + i4);
  float4 vbii = *(const float4*)(bii + h),  vbhi = *(const float4*)(bhi + h);
  float4 vbig = *(const float4*)(big + h),  vbhg = *(const float4*)(bhg + h);
  float4 vbio = *(const float4*)(bio + h),  vbho = *(const float4*)(bho + h);
  float4 vWto = *(const float4*)(Wto + h),  vbto = *(const float4*)(bto + h);
  float4 vbco = *(const float4*)(bco + h);
  float4 vbt1 = *(const float4*)(bit1 + h), vwt1 = *(const float4*)(Wtt1 + h);
  float4 vbt2 = *(const float4*)(bit2 + h), vwt2 = *(const float4*)(Wtt2 + h);

  float4 ocm; ushort4 ocmt; ushort4 oao;
  const unsigned short* pu1 = (const unsigned short*)&u1;
  const unsigned short* pu2 = (const unsigned short*)&u2;
  const unsigned short* pui = (const unsigned short*)&ui;
  const unsigned short* pug = (const unsigned short*)&ug;
  const unsigned short* puo = (const unsigned short*)&uo;
  const float* pcs = (const float*)&cs;
  float* pocm = (float*)&ocm;
  unsigned short* pocmt = (unsigned short*)&ocmt;
  unsigned short* poao = (unsigned short*)&oao;
#pragma unroll
  for (int l = 0; l < 4; ++l) {
    float a1 = bf2f(pu1[l]) + ((const float*)&vbt1)[l];
    float a2 = bf2f(pu2[l]) + ((const float*)&vbt2)[l];
    float ai = bf2f(pui[l]) + ((const float*)&vbii)[l] + ((const float*)&vbhi)[l];
    float ag = bf2f(pug[l]) + ((const float*)&vbig)[l] + ((const float*)&vbhg)[l];
    float ao = bf2f(puo[l]) + ((const float*)&vbio)[l] + ((const float*)&vbho)[l]
             + dt * ((const float*)&vWto)[l] + ((const float*)&vbto)[l] + ((const float*)&vbco)[l];
    float t1 = sigf(a1 + sigf(dt * ((const float*)&vwt1)[l]));
    float t2 = sigf(a2 + sigf(dt * ((const float*)&vwt2)[l]));
    float im = sigf(ai);
    float g  = tanhf(ag);
    float csl = pcs[l];
    float it1 = im * t1;
    float cmt = (1.f - it1) * csl + it1 * g;
    float cm  = (1.f - im) * csl + im * t2 * g;
    pocm[l]  = cm;
    pocmt[l] = f2bf(cmt);
    poao[l]  = f2bf(ao);
  }
  *(float4*)(out_cm + i4) = ocm;
  *(ushort4*)(cmt_b + i4) = ocmt;
  *(ushort4*)(Pre + p + 2048 + h) = oao;   // ao with all biases folded
}

// ---------------- GEMM3 with om/hm epilogue ----------------
__global__ __launch_bounds__(256, 2) void gemm_out(
    const unsigned short* __restrict__ A /*cmt_b BxH*/, const unsigned short* __restrict__ W /*Wco*/,
    const unsigned short* __restrict__ Pre, float* __restrict__ out_hm) {
  __shared__ bf16x8 sA[128 * 8];
  __shared__ bf16x8 sW[128 * 8];
  const int tid  = threadIdx.x;
  const int wave = tid >> 6, lane = tid & 63;
  const int ln15 = lane & 15, kq = lane >> 4;
  const int wr = wave >> 1, wc = wave & 1;
  const long bm = (long)blockIdx.y * 128;
  const long bn = (long)blockIdx.x * 128;
  const int K = H_SZ;

  f32x4 acc[4][4];
#pragma unroll
  for (int i = 0; i < 4; ++i)
#pragma unroll
    for (int j = 0; j < 4; ++j) acc[i][j] = (f32x4){0.f, 0.f, 0.f, 0.f};

  for (int kt = 0; kt < (K >> 6); ++kt) {
    const int k0 = kt << 6;
    __syncthreads();
#pragma unroll
    for (int it = 0; it < 4; ++it) {
      int f   = it * 256 + tid;
      int row = f >> 3;
      int col = (f & 7) << 3;
      int ldsc = it * 256 + wave * 64;
      async_ld16(A + (size_t)(bm + row) * K + k0 + col, (unsigned short*)sA + (size_t)ldsc * 8);
      async_ld16(W + (size_t)(bn + row) * K + k0 + col, (unsigned short*)sW + (size_t)ldsc * 8);
    }
    __syncthreads();
#pragma unroll
    for (int ko = 0; ko < 2; ++ko) {
      bf16x8 af[4], wf[4];
#pragma unroll
      for (int t = 0; t < 4; ++t)
        af[t] = sA[(wr * 64 + t * 16 + ln15) * 8 + ko * 4 + kq];
#pragma unroll
      for (int t = 0; t < 4; ++t)
        wf[t] = sW[(wc * 64 + t * 16 + ln15) * 8 + ko * 4 + kq];
#pragma unroll
      for (int i = 0; i < 4; ++i)
#pragma unroll
        for (int j = 0; j < 4; ++j)
          acc[i][j] = __builtin_amdgcn_mfma_f32_16x16x32_bf16(af[i], wf[j], acc[i][j], 0, 0, 0);
    }
  }
#pragma unroll
  for (int i = 0; i < 4; ++i) {
    const long r0 = bm + wr * 64 + i * 16 + kq * 4;
#pragma unroll
    for (int j = 0; j < 4; ++j) {
      const long c = bn + wc * 64 + j * 16 + ln15;
#pragma unroll
      for (int r = 0; r < 4; ++r) {
        long row = r0 + r;
        size_t idx = (size_t)row * H_SZ + c;
        float ao  = bf2f(Pre[(size_t)row * PRE_LD + 2048 + c]);
        float om  = sigf(ao + acc[i][j][r]);
        float cmt = bf2f(A[idx]);
        out_hm[idx] = om * tanhf(cmt);
      }
    }
  }
}

extern "C" void kernel_launch(void* const* d_in, const int* in_sizes, int n_in,
                              void* d_out, int out_size, void* d_ws, size_t ws_size,
                              hipStream_t stream) {
  const float* x    = (const float*)d_in[0];
  const float* dt   = (const float*)d_in[1];
  const float* hid  = (const float*)d_in[2];
  const float* cell = (const float*)d_in[3];
  const float* Wii  = (const float*)d_in[4];
  const float* bii  = (const float*)d_in[5];
  const float* Whi  = (const float*)d_in[6];
  const float* bhi  = (const float*)d_in[7];
  const float* Wig  = (const float*)d_in[8];
  const float* big  = (const float*)d_in[9];
  const float* Whg  = (const float*)d_in[10];
  const float* bhg  = (const float*)d_in[11];
  const float* Wio  = (const float*)d_in[12];
  const float* bio  = (const float*)d_in[13];
  const float* Who  = (const float*)d_in[14];
  const float* bho  = (const float*)d_in[15];
  const float* Wto  = (const float*)d_in[16];
  const float* bto  = (const float*)d_in[17];
  const float* Wco  = (const float*)d_in[18];
  const float* bco  = (const float*)d_in[19];
  const float* Wit1 = (const float*)d_in[20];
  const float* bit1 = (const float*)d_in[21];
  const float* Wtt1 = (const float*)d_in[22];
  const float* Wit2 = (const float*)d_in[23];
  const float* bit2 = (const float*)d_in[24];
  const float* Wtt2 = (const float*)d_in[25];

  char* wp = (char*)d_ws;
  unsigned short* Ab   = (unsigned short*)wp; wp += (size_t)B_SZ * KC * 2;
  unsigned short* Wall = (unsigned short*)wp; wp += (size_t)NPRE * KC * 2;
  unsigned short* Wcob = (unsigned short*)wp; wp += (size_t)H_SZ * H_SZ * 2;
  unsigned short* Pre  = (unsigned short*)wp; wp += (size_t)B_SZ * PRE_LD * 2;
  unsigned short* Cmtb = (unsigned short*)wp; wp += (size_t)B_SZ * H_SZ * 2;

  float* out = (float*)d_out;

  pack_xh<<<(B_SZ * KC) / 4 / 256, 256, 0, stream>>>(x, hid, Ab);
  WSrcs wsrc;
  wsrc.wx[0] = Wit1; wsrc.wx[1] = Wit2; wsrc.wx[2] = Wii; wsrc.wx[3] = Wig; wsrc.wx[4] = Wio;
  wsrc.wh[0] = Whi;  wsrc.wh[1] = Whg;  wsrc.wh[2] = Who; wsrc.wco = Wco;
  pack_w<<<(NPRE * KC + H_SZ * H_SZ) / 4 / 256, 256, 0, stream>>>(wsrc, Wall, Wcob);

  // Pre = Ab @ Wall^T  (one fused GEMM, K=1024)
  gemm_bt<<<dim3(NPRE / 128, B_SZ / 128), 256, 0, stream>>>(Ab, Wall, Pre, KC, PRE_LD);

  gate_kernel<<<(B_SZ * H_SZ) / 4 / 256, 256, 0, stream>>>(
      Pre, dt, cell, bii, bhi, big, bhg, bio, bho, Wto, bto, bco, bit1, Wtt1, bit2, Wtt2,
      out + (size_t)B_SZ * H_SZ, Cmtb);

  // hm = sig(ao + cmt@Wco^T) * tanh(cmt)
  gemm_out<<<dim3(H_SZ / 128, B_SZ / 128), 256, 0, stream>>>(Cmtb, Wcob, Pre, out);
}

// Round 3
// 233.880 us; speedup vs baseline: 1.1148x; 1.0758x over previous
//
#include <hip/hip_runtime.h>
#include <hip/hip_bf16.h>
#include <stdint.h>

#define B_SZ 8192
#define D_SZ 512
#define H_SZ 512
#define KC 1024       // concatenated K (x | hidden)
#define NPRE 2560     // 5 gate blocks of 512 columns
#define PRE_LD 2560

typedef __attribute__((ext_vector_type(8))) __bf16 bf16x8;
typedef __attribute__((ext_vector_type(4))) float f32x4;

__device__ __forceinline__ unsigned short f2bf(float f) {
  unsigned u = __builtin_bit_cast(unsigned, f);
  u += 0x7FFFu + ((u >> 16) & 1u);   // RNE (inputs finite)
  return (unsigned short)(u >> 16);
}
__device__ __forceinline__ float bf2f(unsigned short h) {
  unsigned u = ((unsigned)h) << 16;
  return __builtin_bit_cast(float, u);
}
__device__ __forceinline__ float sigf(float x) { return 1.0f / (1.0f + __expf(-x)); }

// async 16B global->LDS (wave-uniform LDS base + lane*16)
__device__ __forceinline__ void async_ld16(const unsigned short* g, unsigned short* l) {
  __builtin_amdgcn_global_load_lds(
      (const __attribute__((address_space(1))) unsigned int*)g,
      (__attribute__((address_space(3))) unsigned int*)l, 16, 0, 0);
}

// ---------------- pack kernel (x|h concat cast + weight concat cast) ----------------
struct WSrcs { const float* wx[5]; const float* wh[3]; const float* wco; };

__global__ void pack_all(const float* __restrict__ x, const float* __restrict__ h, WSrcs ws,
                         unsigned short* __restrict__ Ab, unsigned short* __restrict__ Wall,
                         unsigned short* __restrict__ Wcob) {
  int i = (blockIdx.x * 256 + threadIdx.x) * 4;
  const int XH = B_SZ * KC;
  const float* s;
  unsigned short* d;
  if (i < XH) {
    int b = i >> 10, c = i & 1023;
    s = (c < 512) ? (x + (size_t)b * 512 + c) : (h + (size_t)b * 512 + (c - 512));
    d = Ab + i;
  } else if (i < XH + NPRE * KC) {
    int j = i - XH;
    int row = j >> 10, c = j & 1023;
    int gate = row >> 9, r = row & 511;
    d = Wall + j;
    if (c < 512) {
      s = ws.wx[gate] + (size_t)r * 512 + c;
    } else if (gate >= 2) {
      s = ws.wh[gate - 2] + (size_t)r * 512 + (c - 512);
    } else {
      *(ushort4*)d = (ushort4){0, 0, 0, 0};   // t1/t2 hidden half = 0 (skipped in GEMM)
      return;
    }
  } else {
    int j = i - XH - NPRE * KC;
    s = ws.wco + j;
    d = Wcob + j;
  }
  float4 v = *(const float4*)s;
  ushort4 o; o.x = f2bf(v.x); o.y = f2bf(v.y); o.z = f2bf(v.z); o.w = f2bf(v.w);
  *(ushort4*)d = o;
}

// ---------------- GEMM: C[m,n] = A[m,:] . W[n,:]  (bf16 in/out) ----------------
// 128x128 tile, BK=64, 4 waves (2x2), mfma_f32_16x16x32_bf16.
// LDS XOR swizzle: LDS chunk (row, c) holds global chunk (row, c ^ (row&7)) so
// fragment reads (16 lanes, same k-chunk, 16 consecutive rows) spread over all
// 32 banks (was: 16-way conflict, SQ_LDS_BANK_CONFLICT=1.57e7).
__global__ __launch_bounds__(256, 2) void gemm_bt(
    const unsigned short* __restrict__ A, const unsigned short* __restrict__ W,
    unsigned short* __restrict__ C, int K, int ldc) {
  __shared__ bf16x8 sA[128 * 8];
  __shared__ bf16x8 sW[128 * 8];
  const int tid  = threadIdx.x;
  const int wave = tid >> 6, lane = tid & 63;
  const int ln15 = lane & 15, kq = lane >> 4;
  const int wr = wave >> 1, wc = wave & 1;
  const long bm = (long)blockIdx.y * 128;
  const long bn = (long)blockIdx.x * 128;

  f32x4 acc[4][4];
#pragma unroll
  for (int i = 0; i < 4; ++i)
#pragma unroll
    for (int j = 0; j < 4; ++j) acc[i][j] = (f32x4){0.f, 0.f, 0.f, 0.f};

  // t1/t2 gate columns (bn < 1024) have zero weights for k >= 512: skip those k-tiles.
  const int nK = (bn < 1024) ? (512 >> 6) : (K >> 6);
  const int swb = ln15 & 7;   // row&7 for this lane's fragment rows (t*16 preserves mod 8)

  for (int kt = 0; kt < nK; ++kt) {
    const int k0 = kt << 6;
    __syncthreads();
#pragma unroll
    for (int it = 0; it < 4; ++it) {
      int f   = it * 256 + tid;                 // == LDS chunk index this lane fills
      int row = f >> 3;
      int col = ((f & 7) ^ (row & 7)) << 3;     // XOR swizzle on global source chunk
      int ldsc = it * 256 + wave * 64;          // wave-uniform chunk base
      async_ld16(A + (size_t)(bm + row) * K + k0 + col, (unsigned short*)sA + (size_t)ldsc * 8);
      async_ld16(W + (size_t)(bn + row) * K + k0 + col, (unsigned short*)sW + (size_t)ldsc * 8);
    }
    __syncthreads();
#pragma unroll
    for (int ko = 0; ko < 2; ++ko) {
      const int q = (ko * 4 + kq) ^ swb;        // swizzled k-chunk index
      bf16x8 af[4], wf[4];
#pragma unroll
      for (int t = 0; t < 4; ++t)
        af[t] = sA[(wr * 64 + t * 16 + ln15) * 8 + q];
#pragma unroll
      for (int t = 0; t < 4; ++t)
        wf[t] = sW[(wc * 64 + t * 16 + ln15) * 8 + q];
#pragma unroll
      for (int i = 0; i < 4; ++i)
#pragma unroll
        for (int j = 0; j < 4; ++j)
          acc[i][j] = __builtin_amdgcn_mfma_f32_16x16x32_bf16(af[i], wf[j], acc[i][j], 0, 0, 0);
    }
  }
  // C/D layout: col=lane&15, row=(lane>>4)*4+reg
#pragma unroll
  for (int i = 0; i < 4; ++i) {
    const long r0 = bm + wr * 64 + i * 16 + kq * 4;
#pragma unroll
    for (int j = 0; j < 4; ++j) {
      const long c = bn + wc * 64 + j * 16 + ln15;
#pragma unroll
      for (int r = 0; r < 4; ++r)
        C[(size_t)(r0 + r) * ldc + c] = f2bf(acc[i][j][r]);
    }
  }
}

// ---------------- gate kernel (4 elems/thread, vectorized) ----------------
__global__ void gate_kernel(unsigned short* __restrict__ Pre,
                            const float* __restrict__ delta_t, const float* __restrict__ cell_s,
                            const float* __restrict__ bii, const float* __restrict__ bhi,
                            const float* __restrict__ big, const float* __restrict__ bhg,
                            const float* __restrict__ bio, const float* __restrict__ bho,
                            const float* __restrict__ Wto, const float* __restrict__ bto,
                            const float* __restrict__ bco,
                            const float* __restrict__ bit1, const float* __restrict__ Wtt1,
                            const float* __restrict__ bit2, const float* __restrict__ Wtt2,
                            float* __restrict__ out_cm, unsigned short* __restrict__ cmt_b) {
  int i4 = (blockIdx.x * 256 + threadIdx.x) * 4;
  int b = i4 >> 9, h = i4 & 511;
  size_t p = (size_t)b * PRE_LD;
  float dt = delta_t[b];
  ushort4 u1 = *(const ushort4*)(Pre + p + h);
  ushort4 u2 = *(const ushort4*)(Pre + p + 512 + h);
  ushort4 ui = *(const ushort4*)(Pre + p + 1024 + h);
  ushort4 ug = *(const ushort4*)(Pre + p + 1536 + h);
  ushort4 uo = *(const ushort4*)(Pre + p + 2048 + h);
  float4 cs  = *(const float4*)(cell_s + i4);
  float4 vbii = *(const float4*)(bii + h),  vbhi = *(const float4*)(bhi + h);
  float4 vbig = *(const float4*)(big + h),  vbhg = *(const float4*)(bhg + h);
  float4 vbio = *(const float4*)(bio + h),  vbho = *(const float4*)(bho + h);
  float4 vWto = *(const float4*)(Wto + h),  vbto = *(const float4*)(bto + h);
  float4 vbco = *(const float4*)(bco + h);
  float4 vbt1 = *(const float4*)(bit1 + h), vwt1 = *(const float4*)(Wtt1 + h);
  float4 vbt2 = *(const float4*)(bit2 + h), vwt2 = *(const float4*)(Wtt2 + h);

  float4 ocm; ushort4 ocmt; ushort4 oao;
  const unsigned short* pu1 = (const unsigned short*)&u1;
  const unsigned short* pu2 = (const unsigned short*)&u2;
  const unsigned short* pui = (const unsigned short*)&ui;
  const unsigned short* pug = (const unsigned short*)&ug;
  const unsigned short* puo = (const unsigned short*)&uo;
  const float* pcs = (const float*)&cs;
  float* pocm = (float*)&ocm;
  unsigned short* pocmt = (unsigned short*)&ocmt;
  unsigned short* poao = (unsigned short*)&oao;
#pragma unroll
  for (int l = 0; l < 4; ++l) {
    float a1 = bf2f(pu1[l]) + ((const float*)&vbt1)[l];
    float a2 = bf2f(pu2[l]) + ((const float*)&vbt2)[l];
    float ai = bf2f(pui[l]) + ((const float*)&vbii)[l] + ((const float*)&vbhi)[l];
    float ag = bf2f(pug[l]) + ((const float*)&vbig)[l] + ((const float*)&vbhg)[l];
    float ao = bf2f(puo[l]) + ((const float*)&vbio)[l] + ((const float*)&vbho)[l]
             + dt * ((const float*)&vWto)[l] + ((const float*)&vbto)[l] + ((const float*)&vbco)[l];
    float t1 = sigf(a1 + sigf(dt * ((const float*)&vwt1)[l]));
    float t2 = sigf(a2 + sigf(dt * ((const float*)&vwt2)[l]));
    float im = sigf(ai);
    float g  = tanhf(ag);
    float csl = pcs[l];
    float it1 = im * t1;
    float cmt = (1.f - it1) * csl + it1 * g;
    float cm  = (1.f - im) * csl + im * t2 * g;
    pocm[l]  = cm;
    pocmt[l] = f2bf(cmt);
    poao[l]  = f2bf(ao);
  }
  *(float4*)(out_cm + i4) = ocm;
  *(ushort4*)(cmt_b + i4) = ocmt;
  *(ushort4*)(Pre + p + 2048 + h) = oao;   // ao with all biases folded
}

// ---------------- GEMM3 with om/hm epilogue (same swizzle) ----------------
__global__ __launch_bounds__(256, 2) void gemm_out(
    const unsigned short* __restrict__ A /*cmt_b BxH*/, const unsigned short* __restrict__ W /*Wco*/,
    const unsigned short* __restrict__ Pre, float* __restrict__ out_hm) {
  __shared__ bf16x8 sA[128 * 8];
  __shared__ bf16x8 sW[128 * 8];
  const int tid  = threadIdx.x;
  const int wave = tid >> 6, lane = tid & 63;
  const int ln15 = lane & 15, kq = lane >> 4;
  const int wr = wave >> 1, wc = wave & 1;
  const long bm = (long)blockIdx.y * 128;
  const long bn = (long)blockIdx.x * 128;
  const int K = H_SZ;
  const int swb = ln15 & 7;

  f32x4 acc[4][4];
#pragma unroll
  for (int i = 0; i < 4; ++i)
#pragma unroll
    for (int j = 0; j < 4; ++j) acc[i][j] = (f32x4){0.f, 0.f, 0.f, 0.f};

  for (int kt = 0; kt < (K >> 6); ++kt) {
    const int k0 = kt << 6;
    __syncthreads();
#pragma unroll
    for (int it = 0; it < 4; ++it) {
      int f   = it * 256 + tid;
      int row = f >> 3;
      int col = ((f & 7) ^ (row & 7)) << 3;
      int ldsc = it * 256 + wave * 64;
      async_ld16(A + (size_t)(bm + row) * K + k0 + col, (unsigned short*)sA + (size_t)ldsc * 8);
      async_ld16(W + (size_t)(bn + row) * K + k0 + col, (unsigned short*)sW + (size_t)ldsc * 8);
    }
    __syncthreads();
#pragma unroll
    for (int ko = 0; ko < 2; ++ko) {
      const int q = (ko * 4 + kq) ^ swb;
      bf16x8 af[4], wf[4];
#pragma unroll
      for (int t = 0; t < 4; ++t)
        af[t] = sA[(wr * 64 + t * 16 + ln15) * 8 + q];
#pragma unroll
      for (int t = 0; t < 4; ++t)
        wf[t] = sW[(wc * 64 + t * 16 + ln15) * 8 + q];
#pragma unroll
      for (int i = 0; i < 4; ++i)
#pragma unroll
        for (int j = 0; j < 4; ++j)
          acc[i][j] = __builtin_amdgcn_mfma_f32_16x16x32_bf16(af[i], wf[j], acc[i][j], 0, 0, 0);
    }
  }
#pragma unroll
  for (int i = 0; i < 4; ++i) {
    const long r0 = bm + wr * 64 + i * 16 + kq * 4;
#pragma unroll
    for (int j = 0; j < 4; ++j) {
      const long c = bn + wc * 64 + j * 16 + ln15;
#pragma unroll
      for (int r = 0; r < 4; ++r) {
        long row = r0 + r;
        size_t idx = (size_t)row * H_SZ + c;
        float ao  = bf2f(Pre[(size_t)row * PRE_LD + 2048 + c]);
        float om  = sigf(ao + acc[i][j][r]);
        float cmt = bf2f(A[idx]);
        out_hm[idx] = om * tanhf(cmt);
      }
    }
  }
}

extern "C" void kernel_launch(void* const* d_in, const int* in_sizes, int n_in,
                              void* d_out, int out_size, void* d_ws, size_t ws_size,
                              hipStream_t stream) {
  const float* x    = (const float*)d_in[0];
  const float* dt   = (const float*)d_in[1];
  const float* hid  = (const float*)d_in[2];
  const float* cell = (const float*)d_in[3];
  const float* Wii  = (const float*)d_in[4];
  const float* bii  = (const float*)d_in[5];
  const float* Whi  = (const float*)d_in[6];
  const float* bhi  = (const float*)d_in[7];
  const float* Wig  = (const float*)d_in[8];
  const float* big  = (const float*)d_in[9];
  const float* Whg  = (const float*)d_in[10];
  const float* bhg  = (const float*)d_in[11];
  const float* Wio  = (const float*)d_in[12];
  const float* bio  = (const float*)d_in[13];
  const float* Who  = (const float*)d_in[14];
  const float* bho  = (const float*)d_in[15];
  const float* Wto  = (const float*)d_in[16];
  const float* bto  = (const float*)d_in[17];
  const float* Wco  = (const float*)d_in[18];
  const float* bco  = (const float*)d_in[19];
  const float* Wit1 = (const float*)d_in[20];
  const float* bit1 = (const float*)d_in[21];
  const float* Wtt1 = (const float*)d_in[22];
  const float* Wit2 = (const float*)d_in[23];
  const float* bit2 = (const float*)d_in[24];
  const float* Wtt2 = (const float*)d_in[25];

  char* wp = (char*)d_ws;
  unsigned short* Ab   = (unsigned short*)wp; wp += (size_t)B_SZ * KC * 2;
  unsigned short* Wall = (unsigned short*)wp; wp += (size_t)NPRE * KC * 2;
  unsigned short* Wcob = (unsigned short*)wp; wp += (size_t)H_SZ * H_SZ * 2;
  unsigned short* Pre  = (unsigned short*)wp; wp += (size_t)B_SZ * PRE_LD * 2;
  unsigned short* Cmtb = (unsigned short*)wp; wp += (size_t)B_SZ * H_SZ * 2;

  float* out = (float*)d_out;

  WSrcs wsrc;
  wsrc.wx[0] = Wit1; wsrc.wx[1] = Wit2; wsrc.wx[2] = Wii; wsrc.wx[3] = Wig; wsrc.wx[4] = Wio;
  wsrc.wh[0] = Whi;  wsrc.wh[1] = Whg;  wsrc.wh[2] = Who; wsrc.wco = Wco;
  const int pack_elems = B_SZ * KC + NPRE * KC + H_SZ * H_SZ;
  pack_all<<<pack_elems / 4 / 256, 256, 0, stream>>>(x, hid, wsrc, Ab, Wall, Wcob);

  // Pre = Ab @ Wall^T  (one fused GEMM, K=1024; t1/t2 blocks internally run K=512)
  gemm_bt<<<dim3(NPRE / 128, B_SZ / 128), 256, 0, stream>>>(Ab, Wall, Pre, KC, PRE_LD);

  gate_kernel<<<(B_SZ * H_SZ) / 4 / 256, 256, 0, stream>>>(
      Pre, dt, cell, bii, bhi, big, bhg, bio, bho, Wto, bto, bco, bit1, Wtt1, bit2, Wtt2,
      out + (size_t)B_SZ * H_SZ, Cmtb);

  // hm = sig(ao + cmt@Wco^T) * tanh(cmt)
  gemm_out<<<dim3(H_SZ / 128, B_SZ / 128), 256, 0, stream>>>(Cmtb, Wcob, Pre, out);
}